// Round 12
// baseline (31.464 us; speedup 1.0000x reference)
//
#include <hip/hip_runtime.h>

// BipartPool fused: GATv2 bipartite pooling, fully-regular structure.
// lrelu(z) = 0.6z + 0.4|z| -> logit = dot(xl,att6) + xr_att6[r,h] + sum_c |xl+xr|*att4
// No-max softmax (logits ~N(0,1), f32 exp safe): alpha = ex/den; den divided out in k2;
// PV runs on unnormalized ex; den comes free as a ones-column MFMA.
// Base = R11 known-good (absmax 1e-3, 30.5us). ONE change this round: xr table staged
// into LDS (XR4) in phase A; phase D reads it as wave-uniform ds_read_b128 broadcasts
// instead of s_load_dwordx16 streams whose prefetch depth is SGPR-capped. Probes the
// long-standing phase-D SMEM-stall theory cleanly (R9/R10's probe was confounded).

typedef __attribute__((ext_vector_type(8))) short short8;
typedef __attribute__((ext_vector_type(4))) float f32x4;

#define NPG 1024
#define NT 512

static __device__ __forceinline__ unsigned short f2bf(float f) {
    unsigned int u = __float_as_uint(f);
    u += 0x7fffu + ((u >> 16) & 1u);        // RNE (data is normal, no NaN handling)
    return (unsigned short)(u >> 16);
}
static __device__ __forceinline__ float bf2f(unsigned short u) {
    return __uint_as_float(((unsigned int)u) << 16);
}

// ---------------- K0: tables xrT[hc][16r], xr_att6, att6/att4, Wt bf16; batchcent --------
__global__ __launch_bounds__(256) void k0_prep(const float* __restrict__ xcb,
                                               const float* __restrict__ W_l,
                                               const float* __restrict__ W_r,
                                               const float* __restrict__ b_r,
                                               const float* __restrict__ att,
                                               float* __restrict__ xrT,
                                               float* __restrict__ xr_att6,
                                               float* __restrict__ att6,
                                               float* __restrict__ att4,
                                               unsigned short* __restrict__ wt,
                                               float* __restrict__ out) {
    int b = blockIdx.x, t = threadIdx.x;
    if (b < 16) {
        int r = b, hc = t;                  // one wave per head; W_r coalesced over hc
        float v = b_r[hc];
#pragma unroll
        for (int k = 0; k < 64; ++k)
            v = fmaf(xcb[r * 64 + k], W_r[k * 256 + hc], v);
        xrT[hc * 16 + r] = v;               // [hc][16r]: k1 stages into LDS
        float p = 0.6f * att[hc] * v;
        p += __shfl_xor(p, 1);  p += __shfl_xor(p, 2);
        p += __shfl_xor(p, 4);  p += __shfl_xor(p, 8);
        p += __shfl_xor(p, 16); p += __shfl_xor(p, 32);
        if ((t & 63) == 0) xr_att6[r * 4 + (t >> 6)] = p;
    } else {
        att6[t] = 0.6f * att[t];
        att4[t] = 0.4f * att[t];
        // Wt[c][k] = bf16(W_l[k][c])  (k-contiguous for MFMA B-frags)
        unsigned short tmp[64] __attribute__((aligned(16)));
#pragma unroll
        for (int k = 0; k < 64; ++k) tmp[k] = f2bf(W_l[k * 256 + t]);
#pragma unroll
        for (int q = 0; q < 8; ++q)
            *(short8*)(wt + t * 64 + q * 8) = *(const short8*)(tmp + q * 8);
        // batchcent: input-independent
        out[NT * 64 + t]       = (float)(t >> 4);
        out[NT * 64 + 256 + t] = (float)((256 + t) >> 4);
    }
}

// ---------------- K1: fused xl -> logits -> ex -> PV bf16 partials (wave = head) ---------
__global__ __launch_bounds__(256, 2) void k1_fused(const float* __restrict__ x,
                                                   const unsigned short* __restrict__ wt,
                                                   const float* __restrict__ b_l,
                                                   const float* __restrict__ att6,
                                                   const float* __restrict__ att4,
                                                   const float* __restrict__ xrT,
                                                   const float* __restrict__ xr_att6,
                                                   unsigned short* __restrict__ ws_pvh,
                                                   float* __restrict__ ws_denp) {
    __shared__ __align__(16) unsigned char smraw[(256 + 64) * 72 * 2];
    __shared__ __align__(16) float XR4[256][16];   // xr table: phase-D broadcast reads
    unsigned short (*As)[72]  = (unsigned short (*)[72])smraw;             // 64x72 (aliases xlT)
    unsigned short (*xlT)[72] = (unsigned short (*)[72])smraw;             // [h*64+c][n]
    unsigned short (*exT)[72] = (unsigned short (*)[72])(smraw + 256 * 72 * 2); // [h*16+r][n]

    const int t = threadIdx.x;
    const int blk = blockIdx.x;              // 512 tiles of 64 nodes
    const int n0 = blk * 64;

    // ---- phase A: stage x[64n][64k] f32 -> bf16 As; stage XR4 ----
    {
        int n = t >> 2, q = (t & 3) * 16;
        const float* p = x + (size_t)(n0 + n) * 64 + q;
        float4 v0 = *(const float4*)p;
        float4 v1 = *(const float4*)(p + 4);
        float4 v2 = *(const float4*)(p + 8);
        float4 v3 = *(const float4*)(p + 12);
        unsigned short h16[16] __attribute__((aligned(16)));
        h16[0]=f2bf(v0.x); h16[1]=f2bf(v0.y); h16[2]=f2bf(v0.z); h16[3]=f2bf(v0.w);
        h16[4]=f2bf(v1.x); h16[5]=f2bf(v1.y); h16[6]=f2bf(v1.z); h16[7]=f2bf(v1.w);
        h16[8]=f2bf(v2.x); h16[9]=f2bf(v2.y); h16[10]=f2bf(v2.z); h16[11]=f2bf(v2.w);
        h16[12]=f2bf(v3.x); h16[13]=f2bf(v3.y); h16[14]=f2bf(v3.z); h16[15]=f2bf(v3.w);
        *(short8*)(&As[n][q])     = *(const short8*)h16;
        *(short8*)(&As[n][q + 8]) = *(const short8*)(h16 + 8);
        // xr table: thread t copies row t (16 f32 = 64 B), coalesced
        const float4* xr = (const float4*)(xrT + t * 16);
        float4 r0 = xr[0], r1 = xr[1], r2 = xr[2], r3 = xr[3];
        float4* xd = (float4*)(&XR4[t][0]);
        xd[0] = r0; xd[1] = r1; xd[2] = r2; xd[3] = r3;
    }
    __syncthreads();                         // barrier 1: staged tiles visible

    const int l = t & 63;
    const int h = __builtin_amdgcn_readfirstlane(t >> 6);   // wave = head
    const int lm = l & 15, lq = l >> 4;
    const int lk = lq * 8;

    // ---- phase B: MFMA C[64n][64c] = x @ W_l(head h) ----
    short8 af[4][2], bfr[4][2];
#pragma unroll
    for (int mt = 0; mt < 4; ++mt)
#pragma unroll
        for (int ks = 0; ks < 2; ++ks)
            af[mt][ks] = *(const short8*)(&As[mt * 16 + lm][ks * 32 + lk]);
#pragma unroll
    for (int nt = 0; nt < 4; ++nt)
#pragma unroll
        for (int ks = 0; ks < 2; ++ks)
            bfr[nt][ks] = *(const short8*)(wt + (size_t)(h * 64 + nt * 16 + lm) * 64 + ks * 32 + lk);

    f32x4 acc[4][4];
#pragma unroll
    for (int mt = 0; mt < 4; ++mt)
#pragma unroll
        for (int nt = 0; nt < 4; ++nt) { f32x4 z = {0.f,0.f,0.f,0.f}; acc[mt][nt] = z; }
#pragma unroll
    for (int mt = 0; mt < 4; ++mt)
#pragma unroll
        for (int nt = 0; nt < 4; ++nt)
#pragma unroll
            for (int ks = 0; ks < 2; ++ks)
                acc[mt][nt] = __builtin_amdgcn_mfma_f32_16x16x32_bf16(
                    af[mt][ks], bfr[nt][ks], acc[mt][nt], 0, 0, 0);

    __syncthreads();   // barrier 2: all frag reads done; xlT may overwrite x tile

    // ---- phase C: acc(+b_l) -> xlT[h*64+c][n] bf16 ----
    // C layout: col(c) = lm (+nt*16), row(n) = lq*4 + j (+mt*16)   [m89-verified]
#pragma unroll
    for (int nt = 0; nt < 4; ++nt) {
        float bl = b_l[h * 64 + nt * 16 + lm];
#pragma unroll
        for (int mt = 0; mt < 4; ++mt) {
            unsigned int d0 = (unsigned int)f2bf(acc[mt][nt][0] + bl) |
                              ((unsigned int)f2bf(acc[mt][nt][1] + bl) << 16);
            unsigned int d1 = (unsigned int)f2bf(acc[mt][nt][2] + bl) |
                              ((unsigned int)f2bf(acc[mt][nt][3] + bl) << 16);
            *(uint2*)(&xlT[h * 64 + nt * 16 + lm][mt * 16 + lq * 4]) = make_uint2(d0, d1);
        }
    }
    __syncthreads();   // barrier 3: fence uint2 stores vs phase-D short reads (TBAA)

    // ---- phase D: logits; xv from own rows; xr rows = LDS broadcast ds_read_b128 ----
    float base = 0.f;
    float lacc[16];
#pragma unroll
    for (int r = 0; r < 16; ++r) lacc[r] = 0.f;
#pragma unroll 4
    for (int c = 0; c < 64; ++c) {
        int row = h * 64 + c;
        float xv = bf2f(xlT[row][l]);
        base = fmaf(xv, att6[row], base);
        float a4 = att4[row];
        float xr4v[16];
        const float4* xp = (const float4*)(&XR4[row][0]);     // wave-uniform -> broadcast
        *(float4*)(xr4v + 0)  = xp[0];
        *(float4*)(xr4v + 4)  = xp[1];
        *(float4*)(xr4v + 8)  = xp[2];
        *(float4*)(xr4v + 12) = xp[3];
#pragma unroll
        for (int r = 0; r < 16; ++r)
            lacc[r] = fmaf(fabsf(xv + xr4v[r]), a4, lacc[r]); // abs = free VOP3 modifier
    }
#pragma unroll
    for (int r = 0; r < 16; ++r) {
        float ex = __expf(base + lacc[r] + xr_att6[r * 4 + h]);   // no-max softmax
        exT[h * 16 + r][l] = f2bf(ex);
    }
    __syncthreads();   // barrier 4: fence E scalar stores vs phase-E short8 reads

    // ---- phase E: PV MFMA: pacc[16r][64c] = ex^T @ xl ; ones-col B gives den ----
    short8 ap[2];
#pragma unroll
    for (int ks = 0; ks < 2; ++ks)
        ap[ks] = *(const short8*)(&exT[h * 16 + lm][ks * 32 + lk]);
    short o = (lm == 0) ? (short)0x3F80 : (short)0;   // bf16 1.0 in column 0
    short8 onesf = {o, o, o, o, o, o, o, o};

    f32x4 pacc[4], dacc;
    { f32x4 z = {0.f,0.f,0.f,0.f}; pacc[0]=z; pacc[1]=z; pacc[2]=z; pacc[3]=z; dacc=z; }
#pragma unroll
    for (int ks = 0; ks < 2; ++ks) {
#pragma unroll
        for (int nt = 0; nt < 4; ++nt) {
            short8 bp = *(const short8*)(&xlT[h * 64 + nt * 16 + lm][ks * 32 + lk]);
            pacc[nt] = __builtin_amdgcn_mfma_f32_16x16x32_bf16(ap[ks], bp, pacc[nt], 0, 0, 0);
        }
        dacc = __builtin_amdgcn_mfma_f32_16x16x32_bf16(ap[ks], onesf, dacc, 0, 0, 0);
    }

    // ---- store partials: pvh[blk][h][16r][64c] bf16, denp[blk][h][16r] f32 ----
    unsigned short* pvb = ws_pvh + ((size_t)blk * 4 + h) * 1024;
#pragma unroll
    for (int nt = 0; nt < 4; ++nt)
#pragma unroll
        for (int j = 0; j < 4; ++j)
            pvb[(lq * 4 + j) * 64 + nt * 16 + lm] = f2bf(pacc[nt][j]);
    if (lm == 0) {
#pragma unroll
        for (int j = 0; j < 4; ++j)
            ws_denp[((size_t)blk * 4 + h) * 16 + lq * 4 + j] = dacc[j];
    }
}

// ---------------- K2: reduce 16 tiles: out = 0.25*sum_h num/den + bias ------------------
__global__ __launch_bounds__(256) void k2_final(const unsigned short* __restrict__ ws_pvh,
                                                const float* __restrict__ ws_denp,
                                                const float* __restrict__ bias,
                                                float* __restrict__ out) {
    int b = blockIdx.x;                         // 128 = g(32) x rquad(4)
    int g = b >> 2;
    int r = (b & 3) * 4 + (threadIdx.x >> 6);   // wave-uniform -> den via s_loads
    int c = threadIdx.x & 63;
    float acc = 0.f;
#pragma unroll
    for (int h = 0; h < 4; ++h) {
        float num = 0.f, den = 0.f;
#pragma unroll
        for (int tl = 0; tl < 16; ++tl) {
            num += bf2f(ws_pvh[(((size_t)(g * 16 + tl)) * 4 + h) * 1024 + r * 64 + c]);
            den += ws_denp[((size_t)(g * 16 + tl) * 4 + h) * 16 + r];
        }
        acc += num / den;
    }
    out[(size_t)(g * 16 + r) * 64 + c] = fmaf(0.25f, acc, bias[c]);
}

extern "C" void kernel_launch(void* const* d_in, const int* in_sizes, int n_in,
                              void* d_out, int out_size, void* d_ws, size_t ws_size,
                              hipStream_t stream) {
    const float* x    = (const float*)d_in[0];
    const float* xcb  = (const float*)d_in[3];
    const float* W_l  = (const float*)d_in[4];
    const float* b_l  = (const float*)d_in[5];
    const float* W_r  = (const float*)d_in[6];
    const float* b_r  = (const float*)d_in[7];
    const float* att  = (const float*)d_in[8];
    const float* bias = (const float*)d_in[9];
    float* out = (float*)d_out;

    // workspace layout (~4.3 MB)
    unsigned short* ws_pvh = (unsigned short*)d_ws;       // 512 blk x 4 h x 16 r x 64 c bf16
    float* ws_denp = (float*)(ws_pvh + 2097152);          // 512 x 4 x 16 f32
    float* xrT     = ws_denp + 32768;                     // [hc][16r]
    float* xr_att6 = xrT + 4096;                          // 64
    float* att6    = xr_att6 + 64;                        // 256
    float* att4    = att6 + 256;                          // 256
    unsigned short* wt = (unsigned short*)(att4 + 256);   // 256x64 bf16

    k0_prep<<<17, 256, 0, stream>>>(xcb, W_l, W_r, b_r, att, xrT, xr_att6, att6, att4, wt, out);
    k1_fused<<<512, 256, 0, stream>>>(x, wt, b_l, att6, att4, xrT, xr_att6, ws_pvh, ws_denp);
    k2_final<<<128, 256, 0, stream>>>(ws_pvh, ws_denp, bias, out);
}

// Round 13
// 27.754 us; speedup vs baseline: 1.1336x; 1.1336x over previous
//
#include <hip/hip_runtime.h>

// BipartPool fused: GATv2 bipartite pooling, fully-regular structure.
// lrelu(z) = 0.6z + 0.4|z| -> logit = 0.6*dot(xl,att) + s_r(r,h) + sum_c |xl+xr|*0.4att
// No-max softmax (logits ~N(0,1), f32 exp safe): alpha = ex/den; den divided out in k2;
// PV runs on unnormalized ex; den comes free as a ones-column MFMA.
// R12->R13: k0 FUSED into k1 (2 launches). Each block builds its own tables:
//   xr[16r][256hc] = b_r + xcb@W_r via 8 MFMA (xcb bf16-staged in LDS; W_r/W_l B-frags =
//   scattered L2-hot dword loads + v_cvt_pk_bf16_f32). cvt_pk orientation note: pk packs
//   are used ONLY for k-indexed pairs (A-staging and B-frags consistently), where an
//   orientation swap is contraction-invariant. All n-indexed packs (phase C/exT/pv) keep
//   manual f2bf -- an n-pair swap there mislabels nodes (the R9 0.56 bug).
//   s_r = 0.6*dot(xr,att) reduced from MFMA frags via shfl_xor; att scaled inline.

typedef __attribute__((ext_vector_type(8))) short short8;
typedef __attribute__((ext_vector_type(4))) float f32x4;

#define NPG 1024
#define NT 512

static __device__ __forceinline__ unsigned short f2bf(float f) {
    unsigned int u = __float_as_uint(f);
    u += 0x7fffu + ((u >> 16) & 1u);        // RNE (data is normal, no NaN handling)
    return (unsigned short)(u >> 16);
}
static __device__ __forceinline__ float bf2f(unsigned short u) {
    return __uint_as_float(((unsigned int)u) << 16);
}
// packed f32->bf16 pair (k-indexed pairs ONLY; orientation-swap must be invariant)
static __device__ __forceinline__ unsigned int cvt2(float a, float b) {
    unsigned int r;
    asm("v_cvt_pk_bf16_f32 %0, %1, %2" : "=v"(r) : "v"(a), "v"(b));
    return r;
}

// ---------------- K1: tables (fused k0) -> xl -> logits -> ex -> PV bf16 partials --------
__global__ __launch_bounds__(256, 2) void k1_fused(const float* __restrict__ x,
                                                   const float* __restrict__ W_l,
                                                   const float* __restrict__ W_r,
                                                   const float* __restrict__ b_l,
                                                   const float* __restrict__ b_r,
                                                   const float* __restrict__ xcb,
                                                   const float* __restrict__ att,
                                                   unsigned short* __restrict__ ws_pvh,
                                                   float* __restrict__ ws_denp) {
    __shared__ __align__(16) unsigned char smraw[(256 + 64) * 72 * 2];   // 46080 B
    __shared__ __align__(16) float XR4[256][16];                         // 16384 B
    __shared__ float SS[64];                                             // s_r[r*4+h]... [h*16+r]
    unsigned short (*As)[72]  = (unsigned short (*)[72])smraw;           // 64x72 (aliases xlT)
    unsigned short (*xlT)[72] = (unsigned short (*)[72])smraw;           // [h*64+c][n]
    unsigned short (*exT)[72] = (unsigned short (*)[72])(smraw + 256 * 72 * 2); // [h*16+r][n]
    unsigned short (*XCB)[72] = exT;   // rows 0..15 reused as xcb tile until phase B ends

    const int t = threadIdx.x;
    const int blk = blockIdx.x;              // 512 tiles of 64 nodes
    const int n0 = blk * 64;

    // ---- phase A: stage x[64n][64k] f32 -> bf16 As; stage xcb[16][64k] -> XCB ----
    {
        int n = t >> 2, q = (t & 3) * 16;
        const float* p = x + (size_t)(n0 + n) * 64 + q;
        float4 v0 = *(const float4*)p;
        float4 v1 = *(const float4*)(p + 4);
        float4 v2 = *(const float4*)(p + 8);
        float4 v3 = *(const float4*)(p + 12);
        uint4 a, b;
        a.x = cvt2(v0.x, v0.y); a.y = cvt2(v0.z, v0.w);
        a.z = cvt2(v1.x, v1.y); a.w = cvt2(v1.z, v1.w);
        b.x = cvt2(v2.x, v2.y); b.y = cvt2(v2.z, v2.w);
        b.z = cvt2(v3.x, v3.y); b.w = cvt2(v3.z, v3.w);
        *(uint4*)(&As[n][q])     = a;        // barrier 1 fences type-pun vs short8 reads
        *(uint4*)(&As[n][q + 8]) = b;
        // xcb tile: thread t -> row t>>4 (0..15), k quad (t&15)*4
        int rr = t >> 4, k4 = (t & 15) * 4;
        float4 cv = *(const float4*)(xcb + rr * 64 + k4);
        uint2 cw; cw.x = cvt2(cv.x, cv.y); cw.y = cvt2(cv.z, cv.w);
        *(uint2*)(&XCB[rr][k4]) = cw;
    }
    __syncthreads();                         // barrier 1: staged tiles visible

    const int l = t & 63;
    const int h = __builtin_amdgcn_readfirstlane(t >> 6);   // wave = head
    const int lm = l & 15, lq = l >> 4;
    const int lk = lq * 8;

    // ---- phase B: B-frags from raw W_l/W_r (scattered dwords, L2-hot) + MFMAs ----
    short8 af[4][2], bfr[4][2], brf[4][2];
#pragma unroll
    for (int nt = 0; nt < 4; ++nt)
#pragma unroll
        for (int ks = 0; ks < 2; ++ks) {
            const float* wl = W_l + (size_t)(ks * 32 + lk) * 256 + h * 64 + nt * 16 + lm;
            const float* wr = W_r + (size_t)(ks * 32 + lk) * 256 + h * 64 + nt * 16 + lm;
            uint4 pl, pr;
            pl.x = cvt2(wl[0 * 256], wl[1 * 256]); pl.y = cvt2(wl[2 * 256], wl[3 * 256]);
            pl.z = cvt2(wl[4 * 256], wl[5 * 256]); pl.w = cvt2(wl[6 * 256], wl[7 * 256]);
            pr.x = cvt2(wr[0 * 256], wr[1 * 256]); pr.y = cvt2(wr[2 * 256], wr[3 * 256]);
            pr.z = cvt2(wr[4 * 256], wr[5 * 256]); pr.w = cvt2(wr[6 * 256], wr[7 * 256]);
            bfr[nt][ks] = *(short8*)&pl;
            brf[nt][ks] = *(short8*)&pr;
        }
#pragma unroll
    for (int mt = 0; mt < 4; ++mt)
#pragma unroll
        for (int ks = 0; ks < 2; ++ks)
            af[mt][ks] = *(const short8*)(&As[mt * 16 + lm][ks * 32 + lk]);
    short8 axc[2];
#pragma unroll
    for (int ks = 0; ks < 2; ++ks)
        axc[ks] = *(const short8*)(&XCB[lm][ks * 32 + lk]);

    f32x4 acc[4][4], axr[4];
#pragma unroll
    for (int mt = 0; mt < 4; ++mt)
#pragma unroll
        for (int nt = 0; nt < 4; ++nt) { f32x4 z = {0.f,0.f,0.f,0.f}; acc[mt][nt] = z; }
#pragma unroll
    for (int nt = 0; nt < 4; ++nt) { f32x4 z = {0.f,0.f,0.f,0.f}; axr[nt] = z; }
#pragma unroll
    for (int mt = 0; mt < 4; ++mt)
#pragma unroll
        for (int nt = 0; nt < 4; ++nt)
#pragma unroll
            for (int ks = 0; ks < 2; ++ks)
                acc[mt][nt] = __builtin_amdgcn_mfma_f32_16x16x32_bf16(
                    af[mt][ks], bfr[nt][ks], acc[mt][nt], 0, 0, 0);
#pragma unroll
    for (int nt = 0; nt < 4; ++nt)
#pragma unroll
        for (int ks = 0; ks < 2; ++ks)
            axr[nt] = __builtin_amdgcn_mfma_f32_16x16x32_bf16(
                axc[ks], brf[nt][ks], axr[nt], 0, 0, 0);   // xr = xcb @ W_r (head h)

    __syncthreads();   // barrier 2: all frag reads done; xlT may overwrite As/XCB

    // ---- phase C: acc(+b_l) -> xlT[h*64+c][n] bf16 (manual f2bf: n-pairs!) ----
    // C layout: col(c) = lm (+nt*16), row(n) = lq*4 + j (+mt*16)   [m89-verified]
#pragma unroll
    for (int nt = 0; nt < 4; ++nt) {
        float bl = b_l[h * 64 + nt * 16 + lm];
#pragma unroll
        for (int mt = 0; mt < 4; ++mt) {
            unsigned int d0 = (unsigned int)f2bf(acc[mt][nt][0] + bl) |
                              ((unsigned int)f2bf(acc[mt][nt][1] + bl) << 16);
            unsigned int d1 = (unsigned int)f2bf(acc[mt][nt][2] + bl) |
                              ((unsigned int)f2bf(acc[mt][nt][3] + bl) << 16);
            *(uint2*)(&xlT[h * 64 + nt * 16 + lm][mt * 16 + lq * 4]) = make_uint2(d0, d1);
        }
    }
    // xr(+b_r) -> XR4[hc][16r]; s_r partials from frags, shfl-reduce over lm
    {
        float brv[4], atw[4], pj[4];
#pragma unroll
        for (int nt = 0; nt < 4; ++nt) {
            brv[nt] = b_r[h * 64 + nt * 16 + lm];
            atw[nt] = att[h * 64 + nt * 16 + lm];
        }
#pragma unroll
        for (int j = 0; j < 4; ++j) pj[j] = 0.f;
#pragma unroll
        for (int nt = 0; nt < 4; ++nt) {
            float4 w;
            w.x = axr[nt][0] + brv[nt]; w.y = axr[nt][1] + brv[nt];
            w.z = axr[nt][2] + brv[nt]; w.w = axr[nt][3] + brv[nt];
            *(float4*)(&XR4[h * 64 + nt * 16 + lm][lq * 4]) = w;
            pj[0] = fmaf(w.x, atw[nt], pj[0]); pj[1] = fmaf(w.y, atw[nt], pj[1]);
            pj[2] = fmaf(w.z, atw[nt], pj[2]); pj[3] = fmaf(w.w, atw[nt], pj[3]);
        }
#pragma unroll
        for (int j = 0; j < 4; ++j) {
            pj[j] += __shfl_xor(pj[j], 1); pj[j] += __shfl_xor(pj[j], 2);
            pj[j] += __shfl_xor(pj[j], 4); pj[j] += __shfl_xor(pj[j], 8);
        }
        if (lm == 0) {
#pragma unroll
            for (int j = 0; j < 4; ++j) SS[h * 16 + lq * 4 + j] = 0.6f * pj[j];
        }
    }
    __syncthreads();   // barrier 3: fence uint2/float4 stores vs phase-D reads (TBAA)

    // ---- phase D: logits; xr rows = LDS broadcast; att s_load scaled inline ----
    float base = 0.f;
    float lacc[16];
#pragma unroll
    for (int r = 0; r < 16; ++r) lacc[r] = 0.f;
#pragma unroll 4
    for (int c = 0; c < 64; ++c) {
        int row = h * 64 + c;
        float xv = bf2f(xlT[row][l]);
        float attv = att[row];                                // wave-uniform s_load
        base = fmaf(xv, attv, base);
        float a4 = 0.4f * attv;
        float xr4v[16];
        const float4* xp = (const float4*)(&XR4[row][0]);     // wave-uniform -> broadcast
        *(float4*)(xr4v + 0)  = xp[0];
        *(float4*)(xr4v + 4)  = xp[1];
        *(float4*)(xr4v + 8)  = xp[2];
        *(float4*)(xr4v + 12) = xp[3];
#pragma unroll
        for (int r = 0; r < 16; ++r)
            lacc[r] = fmaf(fabsf(xv + xr4v[r]), a4, lacc[r]); // abs = free VOP3 modifier
    }
    base *= 0.6f;
#pragma unroll
    for (int r = 0; r < 16; ++r) {
        float ex = __expf(base + lacc[r] + SS[h * 16 + r]);   // no-max softmax
        exT[h * 16 + r][l] = f2bf(ex);
    }
    __syncthreads();   // barrier 4: fence E scalar stores vs phase-E short8 reads

    // ---- phase E: PV MFMA: pacc[16r][64c] = ex^T @ xl ; ones-col B gives den ----
    short8 ap[2];
#pragma unroll
    for (int ks = 0; ks < 2; ++ks)
        ap[ks] = *(const short8*)(&exT[h * 16 + lm][ks * 32 + lk]);
    short o = (lm == 0) ? (short)0x3F80 : (short)0;   // bf16 1.0 in column 0
    short8 onesf = {o, o, o, o, o, o, o, o};

    f32x4 pacc[4], dacc;
    { f32x4 z = {0.f,0.f,0.f,0.f}; pacc[0]=z; pacc[1]=z; pacc[2]=z; pacc[3]=z; dacc=z; }
#pragma unroll
    for (int ks = 0; ks < 2; ++ks) {
#pragma unroll
        for (int nt = 0; nt < 4; ++nt) {
            short8 bp = *(const short8*)(&xlT[h * 64 + nt * 16 + lm][ks * 32 + lk]);
            pacc[nt] = __builtin_amdgcn_mfma_f32_16x16x32_bf16(ap[ks], bp, pacc[nt], 0, 0, 0);
        }
        dacc = __builtin_amdgcn_mfma_f32_16x16x32_bf16(ap[ks], onesf, dacc, 0, 0, 0);
    }

    // ---- store partials: pvh[blk][h][16r][64c] bf16, denp[blk][h][16r] f32 ----
    unsigned short* pvb = ws_pvh + ((size_t)blk * 4 + h) * 1024;
#pragma unroll
    for (int nt = 0; nt < 4; ++nt)
#pragma unroll
        for (int j = 0; j < 4; ++j)
            pvb[(lq * 4 + j) * 64 + nt * 16 + lm] = f2bf(pacc[nt][j]);
    if (lm == 0) {
#pragma unroll
        for (int j = 0; j < 4; ++j)
            ws_denp[((size_t)blk * 4 + h) * 16 + lq * 4 + j] = dacc[j];
    }
}

// ---------------- K2: reduce 16 tiles: out = 0.25*sum_h num/den + bias; batchcent -------
__global__ __launch_bounds__(256) void k2_final(const unsigned short* __restrict__ ws_pvh,
                                                const float* __restrict__ ws_denp,
                                                const float* __restrict__ bias,
                                                float* __restrict__ out) {
    int b = blockIdx.x;                         // 128 = g(32) x rquad(4); 2 batchcent blocks
    if (b < 128) {
        int g = b >> 2;
        int r = (b & 3) * 4 + (threadIdx.x >> 6);   // wave-uniform -> den via s_loads
        int c = threadIdx.x & 63;
        float acc = 0.f;
#pragma unroll
        for (int h = 0; h < 4; ++h) {
            float num = 0.f, den = 0.f;
#pragma unroll
            for (int tl = 0; tl < 16; ++tl) {
                num += bf2f(ws_pvh[(((size_t)(g * 16 + tl)) * 4 + h) * 1024 + r * 64 + c]);
                den += ws_denp[((size_t)(g * 16 + tl) * 4 + h) * 16 + r];
            }
            acc += num / den;
        }
        out[(size_t)(g * 16 + r) * 64 + c] = fmaf(0.25f, acc, bias[c]);
    } else {
        int tt = (b - 128) * 256 + threadIdx.x;     // batchcent (input-independent)
        out[NT * 64 + tt] = (float)(tt >> 4);
    }
}

extern "C" void kernel_launch(void* const* d_in, const int* in_sizes, int n_in,
                              void* d_out, int out_size, void* d_ws, size_t ws_size,
                              hipStream_t stream) {
    const float* x    = (const float*)d_in[0];
    const float* xcb  = (const float*)d_in[3];
    const float* W_l  = (const float*)d_in[4];
    const float* b_l  = (const float*)d_in[5];
    const float* W_r  = (const float*)d_in[6];
    const float* b_r  = (const float*)d_in[7];
    const float* att  = (const float*)d_in[8];
    const float* bias = (const float*)d_in[9];
    float* out = (float*)d_out;

    // workspace layout (~4.3 MB)
    unsigned short* ws_pvh = (unsigned short*)d_ws;       // 512 blk x 4 h x 16 r x 64 c bf16
    float* ws_denp = (float*)(ws_pvh + 2097152);          // 512 x 4 x 16 f32

    k1_fused<<<512, 256, 0, stream>>>(x, W_l, W_r, b_l, b_r, xcb, att, ws_pvh, ws_denp);
    k2_final<<<130, 256, 0, stream>>>(ws_pvh, ws_denp, bias, out);
}